// Round 1
// baseline (36.606 us; speedup 1.0000x reference)
//
#include <hip/hip_runtime.h>

// SimplestSpline: out[b,c,h,w] = piecewise-linear(raw[b,c,h,w]; params[b, c*16..])
// raw: (8,3,1024,1024) fp32 in [0,1]; params: (8,48) fp32.
// 17 uniform segments on [0,1]; knot values padded with 0 (left) and 1 (right).

#define N_KNOTS 16
#define N_SEG 17           // N_KNOTS + 1
#define N_B 8
#define N_C 3
#define N_BC 24            // N_B * N_C
#define HW (1024 * 1024)
#define LOG2_HW4 18        // log2(HW / 4)

__global__ __launch_bounds__(256) void spline_kernel(
    const float* __restrict__ raw,
    const float* __restrict__ params,
    float* __restrict__ out,
    int n4)
{
    // Per-segment table: .x = y_right(seg), .y = slope(seg), for each of 24 curves.
    __shared__ float2 tab[N_BC][N_SEG];   // 24*17*8 B = 3264 B

    for (int t = threadIdx.x; t < N_BC * N_SEG; t += blockDim.x) {
        int bc  = t / N_SEG;
        int seg = t - bc * N_SEG;
        int b   = bc / N_C;
        int c   = bc - b * N_C;
        const float* p = params + b * (N_C * N_KNOTS) + c * N_KNOTS;
        // ys_pad[k]: k==0 -> 0, k==17 -> 1, else params[k-1]
        float yl = (seg == 0)         ? 0.0f : p[seg - 1];
        float yr = (seg == N_SEG - 1) ? 1.0f : p[seg];
        float2 e;
        e.x = yr;
        e.y = (yr - yl) * 17.0f;      // slope = diff / dx, dx = 1/17 (<=1 ulp vs ref)
        tab[bc][seg] = e;
    }
    __syncthreads();

    const float dx = 1.0f / 17.0f;
    const int stride = gridDim.x * blockDim.x;

    for (int i = blockIdx.x * blockDim.x + threadIdx.x; i < n4; i += stride) {
        float4 x4 = reinterpret_cast<const float4*>(raw)[i];
        int bc = i >> LOG2_HW4;       // which (b,c) plane (4 elems never straddle planes)

        float xs[4] = {x4.x, x4.y, x4.z, x4.w};
        float os[4];
        #pragma unroll
        for (int j = 0; j < 4; ++j) {
            float x = xs[j];
            int idx = (int)floorf(x * 17.0f);
            idx = max(0, min(idx, N_SEG - 1));
            float2 e = tab[bc][idx];            // one ds_read_b64
            float xs_r = (float)(idx + 1) * dx; // right knot x
            os[j] = fmaf(x - xs_r, e.y, e.x);   // == y_right - (xs_r - x)*slope
        }
        reinterpret_cast<float4*>(out)[i] =
            make_float4(os[0], os[1], os[2], os[3]);
    }
}

extern "C" void kernel_launch(void* const* d_in, const int* in_sizes, int n_in,
                              void* d_out, int out_size, void* d_ws, size_t ws_size,
                              hipStream_t stream) {
    const float* raw    = (const float*)d_in[0];
    const float* params = (const float*)d_in[1];
    float* out          = (float*)d_out;

    int n4 = out_size / 4;            // 6,291,456 float4s
    int block = 256;
    int grid = 2048;                  // grid-stride; ~12 float4/thread
    spline_kernel<<<grid, block, 0, stream>>>(raw, params, out, n4);
}

// Round 2
// 35.394 us; speedup vs baseline: 1.0343x; 1.0343x over previous
//
#include <hip/hip_runtime.h>

// SimplestSpline: out[b,c,h,w] = piecewise-linear(raw[b,c,h,w]; params[b, c*16..])
// raw: (8,3,1024,1024) fp32 in [0,1]; params: (8,48) fp32.
// 17 uniform segments on [0,1]; knot values padded with 0 (left) and 1 (right).
//
// R1: exact-cover grid (4096 blocks x 256 thr x 6 float4/thread), all 6 loads
// hoisted up-front for MLP. Table of (y_right, slope) per curve in LDS.

#define N_KNOTS 16
#define N_SEG 17           // N_KNOTS + 1
#define N_B 8
#define N_C 3
#define N_BC 24            // N_B * N_C
#define LOG2_HW4 18        // log2(1024*1024 / 4) — float4s per (b,c) plane

#define BLOCK 256
#define GRID 4096
#define ITERS 6            // GRID*BLOCK*ITERS == 6291456 == B*C*H*W/4

__global__ __launch_bounds__(BLOCK) void spline_kernel(
    const float* __restrict__ raw,
    const float* __restrict__ params,
    float* __restrict__ out)
{
    // Per-segment table: .x = y_right(seg), .y = slope(seg), for each of 24 curves.
    __shared__ float2 tab[N_BC][N_SEG];   // 24*17*8 B = 3264 B

    for (int t = threadIdx.x; t < N_BC * N_SEG; t += BLOCK) {
        int bc  = t / N_SEG;
        int seg = t - bc * N_SEG;
        int b   = bc / N_C;
        int c   = bc - b * N_C;
        const float* p = params + b * (N_C * N_KNOTS) + c * N_KNOTS;
        float yl = (seg == 0)         ? 0.0f : p[seg - 1];
        float yr = (seg == N_SEG - 1) ? 1.0f : p[seg];
        float2 e;
        e.x = yr;
        e.y = (yr - yl) * 17.0f;      // slope = diff/dx, dx = 1/17
        tab[bc][seg] = e;
    }
    __syncthreads();

    const float dx = 1.0f / 17.0f;
    const int base   = blockIdx.x * BLOCK + threadIdx.x;
    const int stride = GRID * BLOCK;   // 1,048,576 float4s

    const float4* __restrict__ in4  = reinterpret_cast<const float4*>(raw);
    float4* __restrict__       out4 = reinterpret_cast<float4*>(out);

    // Issue all 6 loads up-front (static indices -> stays in VGPRs).
    float4 x4[ITERS];
    #pragma unroll
    for (int k = 0; k < ITERS; ++k)
        x4[k] = in4[base + k * stride];

    #pragma unroll
    for (int k = 0; k < ITERS; ++k) {
        const int i  = base + k * stride;
        const int bc = i >> LOG2_HW4;

        float xs[4] = {x4[k].x, x4[k].y, x4[k].z, x4[k].w};
        float os[4];
        #pragma unroll
        for (int j = 0; j < 4; ++j) {
            float x = xs[j];
            int idx = (int)floorf(x * 17.0f);
            idx = max(0, min(idx, N_SEG - 1));
            float2 e = tab[bc][idx];            // one ds_read_b64, bank-conflict-free
            float xs_r = (float)(idx + 1) * dx; // right knot x
            os[j] = fmaf(x - xs_r, e.y, e.x);   // == y_right - (xs_r - x)*slope
        }
        out4[i] = make_float4(os[0], os[1], os[2], os[3]);
    }
}

extern "C" void kernel_launch(void* const* d_in, const int* in_sizes, int n_in,
                              void* d_out, int out_size, void* d_ws, size_t ws_size,
                              hipStream_t stream) {
    const float* raw    = (const float*)d_in[0];
    const float* params = (const float*)d_in[1];
    float* out          = (float*)d_out;

    spline_kernel<<<GRID, BLOCK, 0, stream>>>(raw, params, out);
}